// Round 5
// baseline (660.683 us; speedup 1.0000x reference)
//
#include <hip/hip_runtime.h>

// ---------------------------------------------------------------------------
// 3-layer GCN (PyG GCNConv semantics, add_self_loops=False) on MI355X.
//   deg[dst]++ -> rowptr=exscan(deg), dinv=rsqrt(deg), fillc=rowptr
//   fill CSR (csr_src only, 4B/edge, absolute slot from fillc atomic)
//   per layer: Hs = X@W row-scaled by dinv, written FEATURE-SLICED:
//                Hs[g][node][8]  (g = feature group of 8, slice = 3.2MB)
//              g[i,gf] = dinv[i]*sum_p Hs[g][csr_src[p]][f] + bias -> BN/ReLU
// Agg is XCD-pinned: block's feature group = blockIdx%8; with round-robin
// block->XCD dispatch each XCD re-reads only its own 3.2MB slice -> the ~10x
// per-row reuse (deg~10) hits local L2 instead of L3 (round-4: 256MB/layer
// L3 gather at ~5TB/s = 50us/agg). csr_src nt-loaded, G nt-stored to keep
// the slice resident.
// ---------------------------------------------------------------------------

constexpr int SCAN_T = 256;
constexpr int SCAN_E = 8;
constexpr int SCAN_B = SCAN_T * SCAN_E; // 2048 elems per scan block

__global__ __launch_bounds__(256) void k_count_deg(const int* __restrict__ dst,
                                                   int* __restrict__ deg, int E) {
  int e = blockIdx.x * 256 + threadIdx.x;
  if (e < E) atomicAdd(&deg[dst[e]], 1);
}

__global__ __launch_bounds__(SCAN_T) void k_scan1(const int* __restrict__ deg,
                                                  int* __restrict__ pre,
                                                  int* __restrict__ bsum, int N) {
  __shared__ int ls[SCAN_T];
  int t = threadIdx.x;
  int base = blockIdx.x * SCAN_B + t * SCAN_E;
  int v[SCAN_E];
  int s = 0;
#pragma unroll
  for (int j = 0; j < SCAN_E; ++j) {
    int idx = base + j;
    v[j] = (idx < N) ? deg[idx] : 0;
    s += v[j];
  }
  ls[t] = s;
  __syncthreads();
  for (int off = 1; off < SCAN_T; off <<= 1) {
    int x = 0;
    if (t >= off) x = ls[t - off];
    __syncthreads();
    ls[t] += x;
    __syncthreads();
  }
  if (t == SCAN_T - 1) bsum[blockIdx.x] = ls[t];
  int run = (t > 0) ? ls[t - 1] : 0;
#pragma unroll
  for (int j = 0; j < SCAN_E; ++j) {
    int idx = base + j;
    if (idx < N) pre[idx] = run;
    run += v[j];
  }
}

__global__ __launch_bounds__(SCAN_T) void k_scan2(int* __restrict__ bsum, int nb) {
  __shared__ int ls[SCAN_T];
  int t = threadIdx.x;
  ls[t] = (t < nb) ? bsum[t] : 0;
  __syncthreads();
  for (int off = 1; off < SCAN_T; off <<= 1) {
    int x = 0;
    if (t >= off) x = ls[t - off];
    __syncthreads();
    ls[t] += x;
    __syncthreads();
  }
  if (t < nb) bsum[t] = (t > 0) ? ls[t - 1] : 0;
}

// rowptr += block offset; fillc = rowptr (absolute slot counters); dinv.
__global__ __launch_bounds__(256) void k_scan3(int* __restrict__ rowptr,
                                               int* __restrict__ fillc,
                                               const int* __restrict__ bsum,
                                               const int* __restrict__ deg,
                                               float* __restrict__ dinv,
                                               int N, int E) {
  int i = blockIdx.x * 256 + threadIdx.x;
  if (i < N) {
    int r = rowptr[i] + bsum[i / SCAN_B];
    rowptr[i] = r;
    fillc[i] = r;
    int d = deg[i];
    dinv[i] = (d > 0) ? rsqrtf((float)d) : 0.f;
  }
  if (i == 0) rowptr[N] = E;
}

__global__ __launch_bounds__(256) void k_fill(const int* __restrict__ src,
                                              const int* __restrict__ dst,
                                              int* __restrict__ fillc,
                                              int* __restrict__ csr_src, int E) {
  int e = blockIdx.x * 256 + threadIdx.x;
  if (e >= E) return;
  int p = atomicAdd(&fillc[dst[e]], 1);
  csr_src[p] = src[e];
}

// Hs[g][row][8] = dinv[row] * (X[N,K] @ W[K,F]) sliced by feature group.
// Thread = 4 rows x 4 cols.  X staged in K-chunks (49KB LDS max).
template <int K, int F>
__global__ __launch_bounds__(256) void k_gemm(const float* __restrict__ X,
                                              const float* __restrict__ W,
                                              const float* __restrict__ dinv,
                                              float* __restrict__ Hs, int N) {
  constexpr int CG = F / 4;            // 16 (F=64) or 10 (F=40)
  constexpr int RG = 256 / CG;         // 16 or 25
  constexpr int ROWS = RG * 4;         // 64 or 100
  constexpr int KC = (K > 64) ? 64 : K;
  constexpr int NC = K / KC;
  constexpr int XP = KC + 4;
  __shared__ float Wl[K * F];
  __shared__ float Xl[ROWS * XP];

  const int t = threadIdx.x;
  const int row0 = blockIdx.x * ROWS;

  for (int i = t; i < K * F / 4; i += 256)
    reinterpret_cast<float4*>(Wl)[i] = reinterpret_cast<const float4*>(W)[i];

  const int cg = t % CG;
  const int rg = t / CG;
  float4 a0 = make_float4(0.f, 0.f, 0.f, 0.f);
  float4 a1 = make_float4(0.f, 0.f, 0.f, 0.f);
  float4 a2 = make_float4(0.f, 0.f, 0.f, 0.f);
  float4 a3 = make_float4(0.f, 0.f, 0.f, 0.f);

  for (int c = 0; c < NC; ++c) {
    __syncthreads();
    for (int i = t; i < ROWS * KC / 4; i += 256) {
      int r = (i * 4) / KC, col = (i * 4) % KC;
      int row = row0 + r;
      float4 v = make_float4(0.f, 0.f, 0.f, 0.f);
      if (row < N)
        v = *reinterpret_cast<const float4*>(&X[(size_t)row * K + c * KC + col]);
      *reinterpret_cast<float4*>(&Xl[r * XP + col]) = v;
    }
    __syncthreads();
    if (rg < RG) {
      const float* xr = &Xl[rg * 4 * XP];
      const float* wb = &Wl[c * KC * F + cg * 4];
#pragma unroll 2
      for (int k = 0; k < KC; k += 4) {
        float4 w0 = *reinterpret_cast<const float4*>(&wb[(k + 0) * F]);
        float4 w1 = *reinterpret_cast<const float4*>(&wb[(k + 1) * F]);
        float4 w2 = *reinterpret_cast<const float4*>(&wb[(k + 2) * F]);
        float4 w3 = *reinterpret_cast<const float4*>(&wb[(k + 3) * F]);
        float4 x0 = *reinterpret_cast<const float4*>(&xr[0 * XP + k]);
        float4 x1 = *reinterpret_cast<const float4*>(&xr[1 * XP + k]);
        float4 x2 = *reinterpret_cast<const float4*>(&xr[2 * XP + k]);
        float4 x3 = *reinterpret_cast<const float4*>(&xr[3 * XP + k]);
        a0.x = fmaf(x0.x, w0.x, a0.x); a0.y = fmaf(x0.x, w0.y, a0.y);
        a0.z = fmaf(x0.x, w0.z, a0.z); a0.w = fmaf(x0.x, w0.w, a0.w);
        a1.x = fmaf(x1.x, w0.x, a1.x); a1.y = fmaf(x1.x, w0.y, a1.y);
        a1.z = fmaf(x1.x, w0.z, a1.z); a1.w = fmaf(x1.x, w0.w, a1.w);
        a2.x = fmaf(x2.x, w0.x, a2.x); a2.y = fmaf(x2.x, w0.y, a2.y);
        a2.z = fmaf(x2.x, w0.z, a2.z); a2.w = fmaf(x2.x, w0.w, a2.w);
        a3.x = fmaf(x3.x, w0.x, a3.x); a3.y = fmaf(x3.x, w0.y, a3.y);
        a3.z = fmaf(x3.x, w0.z, a3.z); a3.w = fmaf(x3.x, w0.w, a3.w);

        a0.x = fmaf(x0.y, w1.x, a0.x); a0.y = fmaf(x0.y, w1.y, a0.y);
        a0.z = fmaf(x0.y, w1.z, a0.z); a0.w = fmaf(x0.y, w1.w, a0.w);
        a1.x = fmaf(x1.y, w1.x, a1.x); a1.y = fmaf(x1.y, w1.y, a1.y);
        a1.z = fmaf(x1.y, w1.z, a1.z); a1.w = fmaf(x1.y, w1.w, a1.w);
        a2.x = fmaf(x2.y, w1.x, a2.x); a2.y = fmaf(x2.y, w1.y, a2.y);
        a2.z = fmaf(x2.y, w1.z, a2.z); a2.w = fmaf(x2.y, w1.w, a2.w);
        a3.x = fmaf(x3.y, w1.x, a3.x); a3.y = fmaf(x3.y, w1.y, a3.y);
        a3.z = fmaf(x3.y, w1.z, a3.z); a3.w = fmaf(x3.y, w1.w, a3.w);

        a0.x = fmaf(x0.z, w2.x, a0.x); a0.y = fmaf(x0.z, w2.y, a0.y);
        a0.z = fmaf(x0.z, w2.z, a0.z); a0.w = fmaf(x0.z, w2.w, a0.w);
        a1.x = fmaf(x1.z, w2.x, a1.x); a1.y = fmaf(x1.z, w2.y, a1.y);
        a1.z = fmaf(x1.z, w2.z, a1.z); a1.w = fmaf(x1.z, w2.w, a1.w);
        a2.x = fmaf(x2.z, w2.x, a2.x); a2.y = fmaf(x2.z, w2.y, a2.y);
        a2.z = fmaf(x2.z, w2.z, a2.z); a2.w = fmaf(x2.z, w2.w, a2.w);
        a3.x = fmaf(x3.z, w2.x, a3.x); a3.y = fmaf(x3.z, w2.y, a3.y);
        a3.z = fmaf(x3.z, w2.z, a3.z); a3.w = fmaf(x3.z, w2.w, a3.w);

        a0.x = fmaf(x0.w, w3.x, a0.x); a0.y = fmaf(x0.w, w3.y, a0.y);
        a0.z = fmaf(x0.w, w3.z, a0.z); a0.w = fmaf(x0.w, w3.w, a0.w);
        a1.x = fmaf(x1.w, w3.x, a1.x); a1.y = fmaf(x1.w, w3.y, a1.y);
        a1.z = fmaf(x1.w, w3.z, a1.z); a1.w = fmaf(x1.w, w3.w, a1.w);
        a2.x = fmaf(x2.w, w3.x, a2.x); a2.y = fmaf(x2.w, w3.y, a2.y);
        a2.z = fmaf(x2.w, w3.z, a2.z); a2.w = fmaf(x2.w, w3.w, a2.w);
        a3.x = fmaf(x3.w, w3.x, a3.x); a3.y = fmaf(x3.w, w3.y, a3.y);
        a3.z = fmaf(x3.w, w3.z, a3.z); a3.w = fmaf(x3.w, w3.w, a3.w);
      }
    }
  }

  if (rg < RG) {
    const int row = row0 + rg * 4;
    // sliced store: features cg*4..cg*4+3 -> group cg>>1, offset (cg&1)*4
    float* hp = &Hs[((size_t)(cg >> 1) * N) * 8 + (cg & 1) * 4];
    if (row + 0 < N) {
      float s = dinv[row + 0];
      a0.x *= s; a0.y *= s; a0.z *= s; a0.w *= s;
      *reinterpret_cast<float4*>(&hp[(size_t)(row + 0) * 8]) = a0;
    }
    if (row + 1 < N) {
      float s = dinv[row + 1];
      a1.x *= s; a1.y *= s; a1.z *= s; a1.w *= s;
      *reinterpret_cast<float4*>(&hp[(size_t)(row + 1) * 8]) = a1;
    }
    if (row + 2 < N) {
      float s = dinv[row + 2];
      a2.x *= s; a2.y *= s; a2.z *= s; a2.w *= s;
      *reinterpret_cast<float4*>(&hp[(size_t)(row + 2) * 8]) = a2;
    }
    if (row + 3 < N) {
      float s = dinv[row + 3];
      a3.x *= s; a3.y *= s; a3.z *= s; a3.w *= s;
      *reinterpret_cast<float4*>(&hp[(size_t)(row + 3) * 8]) = a3;
    }
  }
}

// G[i, g*8+f] = BN/ReLU( dinv[i] * sum_p Hs[g][csr_src[p]][f] + bias ).
// Block: feature group g = blockIdx%8 (XCD-pinned), 8 nodes (4 waves x 2).
// Wave lanes: sub=lane>>5 (node), eslot=(lane>>3)&3 (edge), f=lane&7.
template <int F, bool BNR>
__global__ __launch_bounds__(256) void k_agg(const float* __restrict__ Hs,
                                             float* __restrict__ G,
                                             const int* __restrict__ rowptr,
                                             const int* __restrict__ csr_src,
                                             const float* __restrict__ dinv,
                                             const float* __restrict__ bias,
                                             const float* __restrict__ gam,
                                             const float* __restrict__ bet,
                                             const float* __restrict__ mu,
                                             const float* __restrict__ var, int N) {
  constexpr int FG = F / 8;  // 8 (F=64) or 5 (F=40)
  const int g = blockIdx.x & 7;
  if (g >= FG) return;
  const int lane = threadIdx.x & 63;
  const int wv = threadIdx.x >> 6;
  const int sub = lane >> 5;
  const int eslot = (lane >> 3) & 3;
  const int f = lane & 7;
  const int node = (blockIdx.x >> 3) * 8 + wv * 2 + sub;
  int p0 = 0, p1 = 0;
  if (node < N) {
    p0 = rowptr[node];
    p1 = rowptr[node + 1];
  }
  const float* __restrict__ Hg = Hs + (size_t)g * N * 8 + f;
  float a0 = 0.f, a1 = 0.f;
  int p = p0 + eslot;
  for (; p + 4 < p1; p += 8) {
    int s0 = __builtin_nontemporal_load(&csr_src[p]);
    int s1 = __builtin_nontemporal_load(&csr_src[p + 4]);
    a0 += Hg[(size_t)s0 * 8];
    a1 += Hg[(size_t)s1 * 8];
  }
  if (p < p1) {
    int s0 = __builtin_nontemporal_load(&csr_src[p]);
    a0 += Hg[(size_t)s0 * 8];
  }
  float acc = a0 + a1;
  acc += __shfl_xor(acc, 8);
  acc += __shfl_xor(acc, 16);
  if (eslot == 0 && node < N) {
    int fg = g * 8 + f;
    float y = fmaf(dinv[node], acc, bias[fg]);
    if (BNR)
      y = fmaxf((y - mu[fg]) * rsqrtf(var[fg] + 1e-5f) * gam[fg] + bet[fg], 0.f);
    __builtin_nontemporal_store(y, &G[(size_t)node * F + fg]);
  }
}

extern "C" void kernel_launch(void* const* d_in, const int* in_sizes, int n_in,
                              void* d_out, int out_size, void* d_ws, size_t ws_size,
                              hipStream_t stream) {
  const float* x  = (const float*)d_in[0];
  const int*   ei = (const int*)d_in[1];
  const float* W1 = (const float*)d_in[2];
  const float* b1 = (const float*)d_in[3];
  const float* W2 = (const float*)d_in[4];
  const float* b2 = (const float*)d_in[5];
  const float* W3 = (const float*)d_in[6];
  const float* b3 = (const float*)d_in[7];
  const float* g1 = (const float*)d_in[8];
  const float* be1 = (const float*)d_in[9];
  const float* m1 = (const float*)d_in[10];
  const float* v1 = (const float*)d_in[11];
  const float* g2 = (const float*)d_in[12];
  const float* be2 = (const float*)d_in[13];
  const float* m2 = (const float*)d_in[14];
  const float* v2 = (const float*)d_in[15];

  const int N = in_sizes[0] / 128;  // 100000
  const int E = in_sizes[1] / 2;    // 1000000
  const int* src = ei;
  const int* dst = ei + E;

  char* w = (char*)d_ws;
  size_t off = 0;
  auto take = [&](size_t bytes) -> void* {
    void* p = w + off;
    off += (bytes + 511) & ~size_t(511);
    return p;
  };
  int*   deg     = (int*)take((size_t)N * 4);
  size_t zeroB   = off;  // only deg needs zeroing
  int*   fillc   = (int*)take((size_t)N * 4);
  int*   rowptr  = (int*)take(((size_t)N + 1) * 4);
  float* dinv    = (float*)take((size_t)N * 4);
  int*   bsum    = (int*)take((size_t)SCAN_T * 4);
  int*   csr_src = (int*)take((size_t)E * 4);
  float* bufA    = (float*)take((size_t)N * 64 * 4);
  float* bufB    = (float*)take((size_t)N * 64 * 4);
  if (off > ws_size) return;

  const int nb = (N + SCAN_B - 1) / SCAN_B;  // 49
  const int aggBlocks = ((N + 7) / 8) * 8;

  hipMemsetAsync(d_ws, 0, zeroB, stream);
  k_count_deg<<<(E + 255) / 256, 256, 0, stream>>>(dst, deg, E);
  k_scan1<<<nb, SCAN_T, 0, stream>>>(deg, rowptr, bsum, N);
  k_scan2<<<1, SCAN_T, 0, stream>>>(bsum, nb);
  k_scan3<<<(N + 255) / 256, 256, 0, stream>>>(rowptr, fillc, bsum, deg, dinv, N, E);
  k_fill<<<(E + 255) / 256, 256, 0, stream>>>(src, dst, fillc, csr_src, E);

  // layer 1
  k_gemm<128, 64><<<(N + 63) / 64, 256, 0, stream>>>(x, W1, dinv, bufA, N);
  k_agg<64, true><<<aggBlocks, 256, 0, stream>>>(bufA, bufB, rowptr, csr_src,
                                                 dinv, b1, g1, be1, m1, v1, N);
  // layer 2
  k_gemm<64, 64><<<(N + 63) / 64, 256, 0, stream>>>(bufB, W2, dinv, bufA, N);
  k_agg<64, true><<<aggBlocks, 256, 0, stream>>>(bufA, bufB, rowptr, csr_src,
                                                 dinv, b2, g2, be2, m2, v2, N);
  // output layer
  k_gemm<64, 40><<<(N + 99) / 100, 256, 0, stream>>>(bufB, W3, dinv, bufA, N);
  k_agg<40, false><<<aggBlocks, 256, 0, stream>>>(
      bufA, (float*)d_out, rowptr, csr_src, dinv, b3, nullptr, nullptr, nullptr,
      nullptr, N);
}

// Round 6
// 317.235 us; speedup vs baseline: 2.0826x; 2.0826x over previous
//
#include <hip/hip_runtime.h>
#include <hip/hip_fp16.h>

// ---------------------------------------------------------------------------
// 3-layer GCN (PyG GCNConv, add_self_loops=False) on MI355X.
//   deg[dst]++ -> rowptr=exscan(deg), dinv=rsqrt(deg), fillc=rowptr
//   fill CSR (csr_src only, 4B/edge, absolute slot via fillc atomic)
//   per layer: Hh = fp16( dinv[row] * (X@W) )        [gemm epilogue]
//              G[i] = BN/ReLU( dinv[i]*sum_p Hh[csr_src[p],:] + bias )
// Round-5 lesson: feature-sliced agg was issue-bound (8x load instrs) — 
// reverted to wave-per-node/float4-row agg (round-3 structure, ~50us) and
// instead halve gather BYTES with fp16 H (L3-bound at ~5TB/s -> ~2x).
// ---------------------------------------------------------------------------

struct half4 { __half2 a, b; };

constexpr int SCAN_T = 256;
constexpr int SCAN_E = 8;
constexpr int SCAN_B = SCAN_T * SCAN_E; // 2048 elems per scan block

__global__ __launch_bounds__(256) void k_count_deg(const int* __restrict__ dst,
                                                   int* __restrict__ deg, int E) {
  int e = blockIdx.x * 256 + threadIdx.x;
  if (e < E) atomicAdd(&deg[dst[e]], 1);
}

__global__ __launch_bounds__(SCAN_T) void k_scan1(const int* __restrict__ deg,
                                                  int* __restrict__ pre,
                                                  int* __restrict__ bsum, int N) {
  __shared__ int ls[SCAN_T];
  int t = threadIdx.x;
  int base = blockIdx.x * SCAN_B + t * SCAN_E;
  int v[SCAN_E];
  int s = 0;
#pragma unroll
  for (int j = 0; j < SCAN_E; ++j) {
    int idx = base + j;
    v[j] = (idx < N) ? deg[idx] : 0;
    s += v[j];
  }
  ls[t] = s;
  __syncthreads();
  for (int off = 1; off < SCAN_T; off <<= 1) {
    int x = 0;
    if (t >= off) x = ls[t - off];
    __syncthreads();
    ls[t] += x;
    __syncthreads();
  }
  if (t == SCAN_T - 1) bsum[blockIdx.x] = ls[t];
  int run = (t > 0) ? ls[t - 1] : 0;
#pragma unroll
  for (int j = 0; j < SCAN_E; ++j) {
    int idx = base + j;
    if (idx < N) pre[idx] = run;
    run += v[j];
  }
}

__global__ __launch_bounds__(SCAN_T) void k_scan2(int* __restrict__ bsum, int nb) {
  __shared__ int ls[SCAN_T];
  int t = threadIdx.x;
  ls[t] = (t < nb) ? bsum[t] : 0;
  __syncthreads();
  for (int off = 1; off < SCAN_T; off <<= 1) {
    int x = 0;
    if (t >= off) x = ls[t - off];
    __syncthreads();
    ls[t] += x;
    __syncthreads();
  }
  if (t < nb) bsum[t] = (t > 0) ? ls[t - 1] : 0;
}

// rowptr += block offset; fillc = rowptr (absolute slot counters); dinv.
__global__ __launch_bounds__(256) void k_scan3(int* __restrict__ rowptr,
                                               int* __restrict__ fillc,
                                               const int* __restrict__ bsum,
                                               const int* __restrict__ deg,
                                               float* __restrict__ dinv,
                                               int N, int E) {
  int i = blockIdx.x * 256 + threadIdx.x;
  if (i < N) {
    int r = rowptr[i] + bsum[i / SCAN_B];
    rowptr[i] = r;
    fillc[i] = r;
    int d = deg[i];
    dinv[i] = (d > 0) ? rsqrtf((float)d) : 0.f;
  }
  if (i == 0) rowptr[N] = E;
}

__global__ __launch_bounds__(256) void k_fill(const int* __restrict__ src,
                                              const int* __restrict__ dst,
                                              int* __restrict__ fillc,
                                              int* __restrict__ csr_src, int E) {
  int e = blockIdx.x * 256 + threadIdx.x;
  if (e >= E) return;
  int p = atomicAdd(&fillc[dst[e]], 1);
  csr_src[p] = src[e];
}

// Hh[row, :] = fp16( dinv[row] * (X[N,K] @ W[K,F]) ).  Thread = 4 rows x 4
// cols (16 fp32 acc).  Both W and X staged in K-chunks of KC<=64 (LDS ~33KB
// for K=128 -> 4 blocks/CU).
template <int K, int F>
__global__ __launch_bounds__(256) void k_gemm(const float* __restrict__ X,
                                              const float* __restrict__ W,
                                              const float* __restrict__ dinv,
                                              __half* __restrict__ Hh, int N) {
  constexpr int CG = F / 4;            // 16 (F=64) or 10 (F=40)
  constexpr int RG = 256 / CG;         // 16 or 25
  constexpr int ROWS = RG * 4;         // 64 or 100
  constexpr int KC = (K > 64) ? 64 : K;
  constexpr int NC = K / KC;
  constexpr int XP = KC + 4;
  __shared__ float Wl[KC * F];
  __shared__ float Xl[ROWS * XP];

  const int t = threadIdx.x;
  const int row0 = blockIdx.x * ROWS;

  const int cg = t % CG;
  const int rg = t / CG;
  float4 a0 = make_float4(0.f, 0.f, 0.f, 0.f);
  float4 a1 = make_float4(0.f, 0.f, 0.f, 0.f);
  float4 a2 = make_float4(0.f, 0.f, 0.f, 0.f);
  float4 a3 = make_float4(0.f, 0.f, 0.f, 0.f);

  for (int c = 0; c < NC; ++c) {
    __syncthreads();  // previous chunk reads done
    for (int i = t; i < KC * F / 4; i += 256)
      reinterpret_cast<float4*>(Wl)[i] =
          reinterpret_cast<const float4*>(W + c * KC * F)[i];
    for (int i = t; i < ROWS * KC / 4; i += 256) {
      int r = (i * 4) / KC, col = (i * 4) % KC;
      int row = row0 + r;
      float4 v = make_float4(0.f, 0.f, 0.f, 0.f);
      if (row < N)
        v = *reinterpret_cast<const float4*>(&X[(size_t)row * K + c * KC + col]);
      *reinterpret_cast<float4*>(&Xl[r * XP + col]) = v;
    }
    __syncthreads();
    if (rg < RG) {
      const float* xr = &Xl[rg * 4 * XP];
      const float* wb = &Wl[cg * 4];
#pragma unroll 2
      for (int k = 0; k < KC; k += 4) {
        float4 w0 = *reinterpret_cast<const float4*>(&wb[(k + 0) * F]);
        float4 w1 = *reinterpret_cast<const float4*>(&wb[(k + 1) * F]);
        float4 w2 = *reinterpret_cast<const float4*>(&wb[(k + 2) * F]);
        float4 w3 = *reinterpret_cast<const float4*>(&wb[(k + 3) * F]);
        float4 x0 = *reinterpret_cast<const float4*>(&xr[0 * XP + k]);
        float4 x1 = *reinterpret_cast<const float4*>(&xr[1 * XP + k]);
        float4 x2 = *reinterpret_cast<const float4*>(&xr[2 * XP + k]);
        float4 x3 = *reinterpret_cast<const float4*>(&xr[3 * XP + k]);
        a0.x = fmaf(x0.x, w0.x, a0.x); a0.y = fmaf(x0.x, w0.y, a0.y);
        a0.z = fmaf(x0.x, w0.z, a0.z); a0.w = fmaf(x0.x, w0.w, a0.w);
        a1.x = fmaf(x1.x, w0.x, a1.x); a1.y = fmaf(x1.x, w0.y, a1.y);
        a1.z = fmaf(x1.x, w0.z, a1.z); a1.w = fmaf(x1.x, w0.w, a1.w);
        a2.x = fmaf(x2.x, w0.x, a2.x); a2.y = fmaf(x2.x, w0.y, a2.y);
        a2.z = fmaf(x2.x, w0.z, a2.z); a2.w = fmaf(x2.x, w0.w, a2.w);
        a3.x = fmaf(x3.x, w0.x, a3.x); a3.y = fmaf(x3.x, w0.y, a3.y);
        a3.z = fmaf(x3.x, w0.z, a3.z); a3.w = fmaf(x3.x, w0.w, a3.w);

        a0.x = fmaf(x0.y, w1.x, a0.x); a0.y = fmaf(x0.y, w1.y, a0.y);
        a0.z = fmaf(x0.y, w1.z, a0.z); a0.w = fmaf(x0.y, w1.w, a0.w);
        a1.x = fmaf(x1.y, w1.x, a1.x); a1.y = fmaf(x1.y, w1.y, a1.y);
        a1.z = fmaf(x1.y, w1.z, a1.z); a1.w = fmaf(x1.y, w1.w, a1.w);
        a2.x = fmaf(x2.y, w1.x, a2.x); a2.y = fmaf(x2.y, w1.y, a2.y);
        a2.z = fmaf(x2.y, w1.z, a2.z); a2.w = fmaf(x2.y, w1.w, a2.w);
        a3.x = fmaf(x3.y, w1.x, a3.x); a3.y = fmaf(x3.y, w1.y, a3.y);
        a3.z = fmaf(x3.y, w1.z, a3.z); a3.w = fmaf(x3.y, w1.w, a3.w);

        a0.x = fmaf(x0.z, w2.x, a0.x); a0.y = fmaf(x0.z, w2.y, a0.y);
        a0.z = fmaf(x0.z, w2.z, a0.z); a0.w = fmaf(x0.z, w2.w, a0.w);
        a1.x = fmaf(x1.z, w2.x, a1.x); a1.y = fmaf(x1.z, w2.y, a1.y);
        a1.z = fmaf(x1.z, w2.z, a1.z); a1.w = fmaf(x1.z, w2.w, a1.w);
        a2.x = fmaf(x2.z, w2.x, a2.x); a2.y = fmaf(x2.z, w2.y, a2.y);
        a2.z = fmaf(x2.z, w2.z, a2.z); a2.w = fmaf(x2.z, w2.w, a2.w);
        a3.x = fmaf(x3.z, w2.x, a3.x); a3.y = fmaf(x3.z, w2.y, a3.y);
        a3.z = fmaf(x3.z, w2.z, a3.z); a3.w = fmaf(x3.z, w2.w, a3.w);

        a0.x = fmaf(x0.w, w3.x, a0.x); a0.y = fmaf(x0.w, w3.y, a0.y);
        a0.z = fmaf(x0.w, w3.z, a0.z); a0.w = fmaf(x0.w, w3.w, a0.w);
        a1.x = fmaf(x1.w, w3.x, a1.x); a1.y = fmaf(x1.w, w3.y, a1.y);
        a1.z = fmaf(x1.w, w3.z, a1.z); a1.w = fmaf(x1.w, w3.w, a1.w);
        a2.x = fmaf(x2.w, w3.x, a2.x); a2.y = fmaf(x2.w, w3.y, a2.y);
        a2.z = fmaf(x2.w, w3.z, a2.z); a2.w = fmaf(x2.w, w3.w, a2.w);
        a3.x = fmaf(x3.w, w3.x, a3.x); a3.y = fmaf(x3.w, w3.y, a3.y);
        a3.z = fmaf(x3.w, w3.z, a3.z); a3.w = fmaf(x3.w, w3.w, a3.w);
      }
    }
  }

  if (rg < RG) {
    const int col = cg * 4;
    const int row = row0 + rg * 4;
#pragma unroll
    for (int r = 0; r < 4; ++r) {
      if (row + r < N) {
        float4 v = (r == 0) ? a0 : (r == 1) ? a1 : (r == 2) ? a2 : a3;
        float s = dinv[row + r];
        half4 o;
        o.a = __floats2half2_rn(v.x * s, v.y * s);
        o.b = __floats2half2_rn(v.z * s, v.w * s);
        *reinterpret_cast<half4*>(&Hh[(size_t)(row + r) * F + col]) = o;
      }
    }
  }
}

// G[i,:] = BN/ReLU( dinv[i] * sum_p Hh[csr_src[p],:] + bias ).  1 wave/node,
// 4x16-lane groups take every 4th edge; lane gl holds features gl*4..gl*4+3
// (half4 = 8B load, 16 lanes = full fp16 row); unroll x2; shuffle reduce.
template <int F, bool BNR>
__global__ __launch_bounds__(256) void k_agg(const __half* __restrict__ H,
                                             float* __restrict__ G,
                                             const int* __restrict__ rowptr,
                                             const int* __restrict__ csr_src,
                                             const float* __restrict__ dinv,
                                             const float* __restrict__ bias,
                                             const float* __restrict__ gam,
                                             const float* __restrict__ bet,
                                             const float* __restrict__ mu,
                                             const float* __restrict__ var, int N) {
  constexpr int LPG = F / 4;
  int node = (blockIdx.x * 256 + threadIdx.x) >> 6;
  int lane = threadIdx.x & 63;
  if (node >= N) return;
  int g = lane >> 4, gl = lane & 15;
  bool active = gl < LPG;
  int p0 = rowptr[node], p1 = rowptr[node + 1];
  float4 a0 = make_float4(0.f, 0.f, 0.f, 0.f);
  float4 a1 = make_float4(0.f, 0.f, 0.f, 0.f);
  int p = p0 + g;
  for (; p + 4 < p1; p += 8) {
    int s0 = csr_src[p];
    int s1 = csr_src[p + 4];
    if (active) {
      half4 h0 = *reinterpret_cast<const half4*>(&H[(size_t)s0 * F + gl * 4]);
      half4 h1 = *reinterpret_cast<const half4*>(&H[(size_t)s1 * F + gl * 4]);
      float2 l0 = __half22float2(h0.a), u0 = __half22float2(h0.b);
      float2 l1 = __half22float2(h1.a), u1 = __half22float2(h1.b);
      a0.x += l0.x; a0.y += l0.y; a0.z += u0.x; a0.w += u0.y;
      a1.x += l1.x; a1.y += l1.y; a1.z += u1.x; a1.w += u1.y;
    }
  }
  if (p < p1) {
    int s0 = csr_src[p];
    if (active) {
      half4 h0 = *reinterpret_cast<const half4*>(&H[(size_t)s0 * F + gl * 4]);
      float2 l0 = __half22float2(h0.a), u0 = __half22float2(h0.b);
      a0.x += l0.x; a0.y += l0.y; a0.z += u0.x; a0.w += u0.y;
    }
  }
  a0.x += a1.x; a0.y += a1.y; a0.z += a1.z; a0.w += a1.w;
#pragma unroll
  for (int off = 16; off <= 32; off <<= 1) {
    a0.x += __shfl_xor(a0.x, off);
    a0.y += __shfl_xor(a0.y, off);
    a0.z += __shfl_xor(a0.z, off);
    a0.w += __shfl_xor(a0.w, off);
  }
  if (g == 0 && active) {
    int f = gl * 4;
    float di = dinv[node];
    float4 y;
    y.x = fmaf(di, a0.x, bias[f + 0]);
    y.y = fmaf(di, a0.y, bias[f + 1]);
    y.z = fmaf(di, a0.z, bias[f + 2]);
    y.w = fmaf(di, a0.w, bias[f + 3]);
    if (BNR) {
      y.x = fmaxf((y.x - mu[f + 0]) * rsqrtf(var[f + 0] + 1e-5f) * gam[f + 0] + bet[f + 0], 0.f);
      y.y = fmaxf((y.y - mu[f + 1]) * rsqrtf(var[f + 1] + 1e-5f) * gam[f + 1] + bet[f + 1], 0.f);
      y.z = fmaxf((y.z - mu[f + 2]) * rsqrtf(var[f + 2] + 1e-5f) * gam[f + 2] + bet[f + 2], 0.f);
      y.w = fmaxf((y.w - mu[f + 3]) * rsqrtf(var[f + 3] + 1e-5f) * gam[f + 3] + bet[f + 3], 0.f);
    }
    *reinterpret_cast<float4*>(&G[(size_t)node * F + f]) = y;
  }
}

extern "C" void kernel_launch(void* const* d_in, const int* in_sizes, int n_in,
                              void* d_out, int out_size, void* d_ws, size_t ws_size,
                              hipStream_t stream) {
  const float* x  = (const float*)d_in[0];
  const int*   ei = (const int*)d_in[1];
  const float* W1 = (const float*)d_in[2];
  const float* b1 = (const float*)d_in[3];
  const float* W2 = (const float*)d_in[4];
  const float* b2 = (const float*)d_in[5];
  const float* W3 = (const float*)d_in[6];
  const float* b3 = (const float*)d_in[7];
  const float* g1 = (const float*)d_in[8];
  const float* be1 = (const float*)d_in[9];
  const float* m1 = (const float*)d_in[10];
  const float* v1 = (const float*)d_in[11];
  const float* g2 = (const float*)d_in[12];
  const float* be2 = (const float*)d_in[13];
  const float* m2 = (const float*)d_in[14];
  const float* v2 = (const float*)d_in[15];

  const int N = in_sizes[0] / 128;  // 100000
  const int E = in_sizes[1] / 2;    // 1000000
  const int* src = ei;
  const int* dst = ei + E;

  char* w = (char*)d_ws;
  size_t off = 0;
  auto take = [&](size_t bytes) -> void* {
    void* p = w + off;
    off += (bytes + 511) & ~size_t(511);
    return p;
  };
  int*    deg     = (int*)take((size_t)N * 4);
  size_t  zeroB   = off;  // only deg needs zeroing
  int*    fillc   = (int*)take((size_t)N * 4);
  int*    rowptr  = (int*)take(((size_t)N + 1) * 4);
  float*  dinv    = (float*)take((size_t)N * 4);
  int*    bsum    = (int*)take((size_t)SCAN_T * 4);
  int*    csr_src = (int*)take((size_t)E * 4);
  __half* Hh      = (__half*)take((size_t)N * 64 * 2);
  float*  Gf      = (float*)take((size_t)N * 64 * 4);
  if (off > ws_size) return;

  const int nb = (N + SCAN_B - 1) / SCAN_B;  // 49

  hipMemsetAsync(d_ws, 0, zeroB, stream);
  k_count_deg<<<(E + 255) / 256, 256, 0, stream>>>(dst, deg, E);
  k_scan1<<<nb, SCAN_T, 0, stream>>>(deg, rowptr, bsum, N);
  k_scan2<<<1, SCAN_T, 0, stream>>>(bsum, nb);
  k_scan3<<<(N + 255) / 256, 256, 0, stream>>>(rowptr, fillc, bsum, deg, dinv, N, E);
  k_fill<<<(E + 255) / 256, 256, 0, stream>>>(src, dst, fillc, csr_src, E);

  // layer 1
  k_gemm<128, 64><<<(N + 63) / 64, 256, 0, stream>>>(x, W1, dinv, Hh, N);
  k_agg<64, true><<<(N + 3) / 4, 256, 0, stream>>>(Hh, Gf, rowptr, csr_src,
                                                   dinv, b1, g1, be1, m1, v1, N);
  // layer 2
  k_gemm<64, 64><<<(N + 63) / 64, 256, 0, stream>>>(Gf, W2, dinv, Hh, N);
  k_agg<64, true><<<(N + 3) / 4, 256, 0, stream>>>(Hh, Gf, rowptr, csr_src,
                                                   dinv, b2, g2, be2, m2, v2, N);
  // output layer
  k_gemm<64, 40><<<(N + 99) / 100, 256, 0, stream>>>(Gf, W3, dinv, Hh, N);
  k_agg<40, false><<<(N + 3) / 4, 256, 0, stream>>>(
      Hh, (float*)d_out, rowptr, csr_src, dinv, b3, nullptr, nullptr, nullptr,
      nullptr, N);
}

// Round 7
// 293.661 us; speedup vs baseline: 2.2498x; 1.0803x over previous
//
#include <hip/hip_runtime.h>
#include <hip/hip_fp16.h>

// ---------------------------------------------------------------------------
// 3-layer GCN (PyG GCNConv, add_self_loops=False) on MI355X.
//   deg[dst]++ (XCD-partitioned) -> rowptr=exscan(deg), dinv=rsqrt(deg),
//   fillc=rowptr -> fill CSR (XCD-partitioned; csr_src only, 4B/edge)
//   per layer: Hh = fp16( dinv[row] * (X@W) )        [gemm epilogue]
//              G[i] = BN/ReLU( dinv[i]*sum_p Hh[csr_src[p],:] + bias )
// Round-6 profile: fill = 70us, WRITE_SIZE 69MB for 4MB payload (random 4B
// scatter -> ~8 partial-line writebacks/line across 8 non-coherent L2s).
// Fix: partition dst-node space 8 ways, p=blockIdx%8 (round-robin -> XCD-
// pinned); each partition's scatter targets (~550KB) stay L2-resident.
// Edge arrays re-read 8x (L3-served, ~13us) -- cheap vs write-amp.
// ---------------------------------------------------------------------------

struct half4 { __half2 a, b; };

constexpr int SCAN_T = 256;
constexpr int SCAN_E = 8;
constexpr int SCAN_B = SCAN_T * SCAN_E; // 2048 elems per scan block
constexpr int NPART = 8;
constexpr int ECHUNK = 2048;            // edges per partition-block

__global__ __launch_bounds__(256) void k_count_deg(const int* __restrict__ dst,
                                                   int* __restrict__ deg,
                                                   int E, int PS) {
  const int p = blockIdx.x & 7;
  const int lo = p * PS, hi = lo + PS;
  const int base = (blockIdx.x >> 3) * ECHUNK + threadIdx.x * 4;
#pragma unroll
  for (int h = 0; h < 2; ++h) {
    int e = base + h * 1024;
    if (e + 3 < E) {
      int4 d4 = *reinterpret_cast<const int4*>(&dst[e]);
      if (d4.x >= lo && d4.x < hi) atomicAdd(&deg[d4.x], 1);
      if (d4.y >= lo && d4.y < hi) atomicAdd(&deg[d4.y], 1);
      if (d4.z >= lo && d4.z < hi) atomicAdd(&deg[d4.z], 1);
      if (d4.w >= lo && d4.w < hi) atomicAdd(&deg[d4.w], 1);
    } else {
      for (int j = 0; j < 4; ++j) {
        int ee = e + j;
        if (ee < E) {
          int d = dst[ee];
          if (d >= lo && d < hi) atomicAdd(&deg[d], 1);
        }
      }
    }
  }
}

__global__ __launch_bounds__(SCAN_T) void k_scan1(const int* __restrict__ deg,
                                                  int* __restrict__ pre,
                                                  int* __restrict__ bsum, int N) {
  __shared__ int ls[SCAN_T];
  int t = threadIdx.x;
  int base = blockIdx.x * SCAN_B + t * SCAN_E;
  int v[SCAN_E];
  int s = 0;
#pragma unroll
  for (int j = 0; j < SCAN_E; ++j) {
    int idx = base + j;
    v[j] = (idx < N) ? deg[idx] : 0;
    s += v[j];
  }
  ls[t] = s;
  __syncthreads();
  for (int off = 1; off < SCAN_T; off <<= 1) {
    int x = 0;
    if (t >= off) x = ls[t - off];
    __syncthreads();
    ls[t] += x;
    __syncthreads();
  }
  if (t == SCAN_T - 1) bsum[blockIdx.x] = ls[t];
  int run = (t > 0) ? ls[t - 1] : 0;
#pragma unroll
  for (int j = 0; j < SCAN_E; ++j) {
    int idx = base + j;
    if (idx < N) pre[idx] = run;
    run += v[j];
  }
}

__global__ __launch_bounds__(SCAN_T) void k_scan2(int* __restrict__ bsum, int nb) {
  __shared__ int ls[SCAN_T];
  int t = threadIdx.x;
  ls[t] = (t < nb) ? bsum[t] : 0;
  __syncthreads();
  for (int off = 1; off < SCAN_T; off <<= 1) {
    int x = 0;
    if (t >= off) x = ls[t - off];
    __syncthreads();
    ls[t] += x;
    __syncthreads();
  }
  if (t < nb) bsum[t] = (t > 0) ? ls[t - 1] : 0;
}

// rowptr += block offset; fillc = rowptr (absolute slot counters); dinv.
__global__ __launch_bounds__(256) void k_scan3(int* __restrict__ rowptr,
                                               int* __restrict__ fillc,
                                               const int* __restrict__ bsum,
                                               const int* __restrict__ deg,
                                               float* __restrict__ dinv,
                                               int N, int E) {
  int i = blockIdx.x * 256 + threadIdx.x;
  if (i < N) {
    int r = rowptr[i] + bsum[i / SCAN_B];
    rowptr[i] = r;
    fillc[i] = r;
    int d = deg[i];
    dinv[i] = (d > 0) ? rsqrtf((float)d) : 0.f;
  }
  if (i == 0) rowptr[N] = E;
}

__global__ __launch_bounds__(256) void k_fill(const int* __restrict__ src,
                                              const int* __restrict__ dst,
                                              int* __restrict__ fillc,
                                              int* __restrict__ csr_src,
                                              int E, int PS) {
  const int p = blockIdx.x & 7;
  const int lo = p * PS, hi = lo + PS;
  const int base = (blockIdx.x >> 3) * ECHUNK + threadIdx.x * 4;
#pragma unroll
  for (int h = 0; h < 2; ++h) {
    int e = base + h * 1024;
    if (e + 3 < E) {
      int4 d4 = *reinterpret_cast<const int4*>(&dst[e]);
      int4 s4 = *reinterpret_cast<const int4*>(&src[e]);
      if (d4.x >= lo && d4.x < hi) csr_src[atomicAdd(&fillc[d4.x], 1)] = s4.x;
      if (d4.y >= lo && d4.y < hi) csr_src[atomicAdd(&fillc[d4.y], 1)] = s4.y;
      if (d4.z >= lo && d4.z < hi) csr_src[atomicAdd(&fillc[d4.z], 1)] = s4.z;
      if (d4.w >= lo && d4.w < hi) csr_src[atomicAdd(&fillc[d4.w], 1)] = s4.w;
    } else {
      for (int j = 0; j < 4; ++j) {
        int ee = e + j;
        if (ee < E) {
          int d = dst[ee];
          if (d >= lo && d < hi) csr_src[atomicAdd(&fillc[d], 1)] = src[ee];
        }
      }
    }
  }
}

// Hh[row, :] = fp16( dinv[row] * (X[N,K] @ W[K,F]) ).  Thread = 4 rows x 4
// cols (16 fp32 acc).  W and X staged in K-chunks of KC<=64 (LDS ~33KB for
// K=128 -> 4 blocks/CU).
template <int K, int F>
__global__ __launch_bounds__(256) void k_gemm(const float* __restrict__ X,
                                              const float* __restrict__ W,
                                              const float* __restrict__ dinv,
                                              __half* __restrict__ Hh, int N) {
  constexpr int CG = F / 4;            // 16 (F=64) or 10 (F=40)
  constexpr int RG = 256 / CG;         // 16 or 25
  constexpr int ROWS = RG * 4;         // 64 or 100
  constexpr int KC = (K > 64) ? 64 : K;
  constexpr int NC = K / KC;
  constexpr int XP = KC + 4;
  __shared__ float Wl[KC * F];
  __shared__ float Xl[ROWS * XP];

  const int t = threadIdx.x;
  const int row0 = blockIdx.x * ROWS;

  const int cg = t % CG;
  const int rg = t / CG;
  float4 a0 = make_float4(0.f, 0.f, 0.f, 0.f);
  float4 a1 = make_float4(0.f, 0.f, 0.f, 0.f);
  float4 a2 = make_float4(0.f, 0.f, 0.f, 0.f);
  float4 a3 = make_float4(0.f, 0.f, 0.f, 0.f);

  for (int c = 0; c < NC; ++c) {
    __syncthreads();  // previous chunk reads done
    for (int i = t; i < KC * F / 4; i += 256)
      reinterpret_cast<float4*>(Wl)[i] =
          reinterpret_cast<const float4*>(W + c * KC * F)[i];
    for (int i = t; i < ROWS * KC / 4; i += 256) {
      int r = (i * 4) / KC, col = (i * 4) % KC;
      int row = row0 + r;
      float4 v = make_float4(0.f, 0.f, 0.f, 0.f);
      if (row < N)
        v = *reinterpret_cast<const float4*>(&X[(size_t)row * K + c * KC + col]);
      *reinterpret_cast<float4*>(&Xl[r * XP + col]) = v;
    }
    __syncthreads();
    if (rg < RG) {
      const float* xr = &Xl[rg * 4 * XP];
      const float* wb = &Wl[cg * 4];
#pragma unroll 2
      for (int k = 0; k < KC; k += 4) {
        float4 w0 = *reinterpret_cast<const float4*>(&wb[(k + 0) * F]);
        float4 w1 = *reinterpret_cast<const float4*>(&wb[(k + 1) * F]);
        float4 w2 = *reinterpret_cast<const float4*>(&wb[(k + 2) * F]);
        float4 w3 = *reinterpret_cast<const float4*>(&wb[(k + 3) * F]);
        float4 x0 = *reinterpret_cast<const float4*>(&xr[0 * XP + k]);
        float4 x1 = *reinterpret_cast<const float4*>(&xr[1 * XP + k]);
        float4 x2 = *reinterpret_cast<const float4*>(&xr[2 * XP + k]);
        float4 x3 = *reinterpret_cast<const float4*>(&xr[3 * XP + k]);
        a0.x = fmaf(x0.x, w0.x, a0.x); a0.y = fmaf(x0.x, w0.y, a0.y);
        a0.z = fmaf(x0.x, w0.z, a0.z); a0.w = fmaf(x0.x, w0.w, a0.w);
        a1.x = fmaf(x1.x, w0.x, a1.x); a1.y = fmaf(x1.x, w0.y, a1.y);
        a1.z = fmaf(x1.x, w0.z, a1.z); a1.w = fmaf(x1.x, w0.w, a1.w);
        a2.x = fmaf(x2.x, w0.x, a2.x); a2.y = fmaf(x2.x, w0.y, a2.y);
        a2.z = fmaf(x2.x, w0.z, a2.z); a2.w = fmaf(x2.x, w0.w, a2.w);
        a3.x = fmaf(x3.x, w0.x, a3.x); a3.y = fmaf(x3.x, w0.y, a3.y);
        a3.z = fmaf(x3.x, w0.z, a3.z); a3.w = fmaf(x3.x, w0.w, a3.w);

        a0.x = fmaf(x0.y, w1.x, a0.x); a0.y = fmaf(x0.y, w1.y, a0.y);
        a0.z = fmaf(x0.y, w1.z, a0.z); a0.w = fmaf(x0.y, w1.w, a0.w);
        a1.x = fmaf(x1.y, w1.x, a1.x); a1.y = fmaf(x1.y, w1.y, a1.y);
        a1.z = fmaf(x1.y, w1.z, a1.z); a1.w = fmaf(x1.y, w1.w, a1.w);
        a2.x = fmaf(x2.y, w1.x, a2.x); a2.y = fmaf(x2.y, w1.y, a2.y);
        a2.z = fmaf(x2.y, w1.z, a2.z); a2.w = fmaf(x2.y, w1.w, a2.w);
        a3.x = fmaf(x3.y, w1.x, a3.x); a3.y = fmaf(x3.y, w1.y, a3.y);
        a3.z = fmaf(x3.y, w1.z, a3.z); a3.w = fmaf(x3.y, w1.w, a3.w);

        a0.x = fmaf(x0.z, w2.x, a0.x); a0.y = fmaf(x0.z, w2.y, a0.y);
        a0.z = fmaf(x0.z, w2.z, a0.z); a0.w = fmaf(x0.z, w2.w, a0.w);
        a1.x = fmaf(x1.z, w2.x, a1.x); a1.y = fmaf(x1.z, w2.y, a1.y);
        a1.z = fmaf(x1.z, w2.z, a1.z); a1.w = fmaf(x1.z, w2.w, a1.w);
        a2.x = fmaf(x2.z, w2.x, a2.x); a2.y = fmaf(x2.z, w2.y, a2.y);
        a2.z = fmaf(x2.z, w2.z, a2.z); a2.w = fmaf(x2.z, w2.w, a2.w);
        a3.x = fmaf(x3.z, w2.x, a3.x); a3.y = fmaf(x3.z, w2.y, a3.y);
        a3.z = fmaf(x3.z, w2.z, a3.z); a3.w = fmaf(x3.z, w2.w, a3.w);

        a0.x = fmaf(x0.w, w3.x, a0.x); a0.y = fmaf(x0.w, w3.y, a0.y);
        a0.z = fmaf(x0.w, w3.z, a0.z); a0.w = fmaf(x0.w, w3.w, a0.w);
        a1.x = fmaf(x1.w, w3.x, a1.x); a1.y = fmaf(x1.w, w3.y, a1.y);
        a1.z = fmaf(x1.w, w3.z, a1.z); a1.w = fmaf(x1.w, w3.w, a1.w);
        a2.x = fmaf(x2.w, w3.x, a2.x); a2.y = fmaf(x2.w, w3.y, a2.y);
        a2.z = fmaf(x2.w, w3.z, a2.z); a2.w = fmaf(x2.w, w3.w, a2.w);
        a3.x = fmaf(x3.w, w3.x, a3.x); a3.y = fmaf(x3.w, w3.y, a3.y);
        a3.z = fmaf(x3.w, w3.z, a3.z); a3.w = fmaf(x3.w, w3.w, a3.w);
      }
    }
  }

  if (rg < RG) {
    const int col = cg * 4;
    const int row = row0 + rg * 4;
#pragma unroll
    for (int r = 0; r < 4; ++r) {
      if (row + r < N) {
        float4 v = (r == 0) ? a0 : (r == 1) ? a1 : (r == 2) ? a2 : a3;
        float s = dinv[row + r];
        half4 o;
        o.a = __floats2half2_rn(v.x * s, v.y * s);
        o.b = __floats2half2_rn(v.z * s, v.w * s);
        *reinterpret_cast<half4*>(&Hh[(size_t)(row + r) * F + col]) = o;
      }
    }
  }
}

// G[i,:] = BN/ReLU( dinv[i] * sum_p Hh[csr_src[p],:] + bias ).  1 wave/node,
// 4x16-lane groups take every 4th edge; lane gl holds features gl*4..gl*4+3
// (half4 = 8B load, 16 lanes = full fp16 row); unroll x2; shuffle reduce.
template <int F, bool BNR>
__global__ __launch_bounds__(256) void k_agg(const __half* __restrict__ H,
                                             float* __restrict__ G,
                                             const int* __restrict__ rowptr,
                                             const int* __restrict__ csr_src,
                                             const float* __restrict__ dinv,
                                             const float* __restrict__ bias,
                                             const float* __restrict__ gam,
                                             const float* __restrict__ bet,
                                             const float* __restrict__ mu,
                                             const float* __restrict__ var, int N) {
  constexpr int LPG = F / 4;
  int node = (blockIdx.x * 256 + threadIdx.x) >> 6;
  int lane = threadIdx.x & 63;
  if (node >= N) return;
  int g = lane >> 4, gl = lane & 15;
  bool active = gl < LPG;
  int p0 = rowptr[node], p1 = rowptr[node + 1];
  float4 a0 = make_float4(0.f, 0.f, 0.f, 0.f);
  float4 a1 = make_float4(0.f, 0.f, 0.f, 0.f);
  int p = p0 + g;
  for (; p + 4 < p1; p += 8) {
    int s0 = csr_src[p];
    int s1 = csr_src[p + 4];
    if (active) {
      half4 h0 = *reinterpret_cast<const half4*>(&H[(size_t)s0 * F + gl * 4]);
      half4 h1 = *reinterpret_cast<const half4*>(&H[(size_t)s1 * F + gl * 4]);
      float2 l0 = __half22float2(h0.a), u0 = __half22float2(h0.b);
      float2 l1 = __half22float2(h1.a), u1 = __half22float2(h1.b);
      a0.x += l0.x; a0.y += l0.y; a0.z += u0.x; a0.w += u0.y;
      a1.x += l1.x; a1.y += l1.y; a1.z += u1.x; a1.w += u1.y;
    }
  }
  if (p < p1) {
    int s0 = csr_src[p];
    if (active) {
      half4 h0 = *reinterpret_cast<const half4*>(&H[(size_t)s0 * F + gl * 4]);
      float2 l0 = __half22float2(h0.a), u0 = __half22float2(h0.b);
      a0.x += l0.x; a0.y += l0.y; a0.z += u0.x; a0.w += u0.y;
    }
  }
  a0.x += a1.x; a0.y += a1.y; a0.z += a1.z; a0.w += a1.w;
#pragma unroll
  for (int off = 16; off <= 32; off <<= 1) {
    a0.x += __shfl_xor(a0.x, off);
    a0.y += __shfl_xor(a0.y, off);
    a0.z += __shfl_xor(a0.z, off);
    a0.w += __shfl_xor(a0.w, off);
  }
  if (g == 0 && active) {
    int f = gl * 4;
    float di = dinv[node];
    float4 y;
    y.x = fmaf(di, a0.x, bias[f + 0]);
    y.y = fmaf(di, a0.y, bias[f + 1]);
    y.z = fmaf(di, a0.z, bias[f + 2]);
    y.w = fmaf(di, a0.w, bias[f + 3]);
    if (BNR) {
      y.x = fmaxf((y.x - mu[f + 0]) * rsqrtf(var[f + 0] + 1e-5f) * gam[f + 0] + bet[f + 0], 0.f);
      y.y = fmaxf((y.y - mu[f + 1]) * rsqrtf(var[f + 1] + 1e-5f) * gam[f + 1] + bet[f + 1], 0.f);
      y.z = fmaxf((y.z - mu[f + 2]) * rsqrtf(var[f + 2] + 1e-5f) * gam[f + 2] + bet[f + 2], 0.f);
      y.w = fmaxf((y.w - mu[f + 3]) * rsqrtf(var[f + 3] + 1e-5f) * gam[f + 3] + bet[f + 3], 0.f);
    }
    *reinterpret_cast<float4*>(&G[(size_t)node * F + f]) = y;
  }
}

extern "C" void kernel_launch(void* const* d_in, const int* in_sizes, int n_in,
                              void* d_out, int out_size, void* d_ws, size_t ws_size,
                              hipStream_t stream) {
  const float* x  = (const float*)d_in[0];
  const int*   ei = (const int*)d_in[1];
  const float* W1 = (const float*)d_in[2];
  const float* b1 = (const float*)d_in[3];
  const float* W2 = (const float*)d_in[4];
  const float* b2 = (const float*)d_in[5];
  const float* W3 = (const float*)d_in[6];
  const float* b3 = (const float*)d_in[7];
  const float* g1 = (const float*)d_in[8];
  const float* be1 = (const float*)d_in[9];
  const float* m1 = (const float*)d_in[10];
  const float* v1 = (const float*)d_in[11];
  const float* g2 = (const float*)d_in[12];
  const float* be2 = (const float*)d_in[13];
  const float* m2 = (const float*)d_in[14];
  const float* v2 = (const float*)d_in[15];

  const int N = in_sizes[0] / 128;  // 100000
  const int E = in_sizes[1] / 2;    // 1000000
  const int* src = ei;
  const int* dst = ei + E;

  char* w = (char*)d_ws;
  size_t off = 0;
  auto take = [&](size_t bytes) -> void* {
    void* p = w + off;
    off += (bytes + 511) & ~size_t(511);
    return p;
  };
  int*    deg     = (int*)take((size_t)N * 4);
  size_t  zeroB   = off;  // only deg needs zeroing
  int*    fillc   = (int*)take((size_t)N * 4);
  int*    rowptr  = (int*)take(((size_t)N + 1) * 4);
  float*  dinv    = (float*)take((size_t)N * 4);
  int*    bsum    = (int*)take((size_t)SCAN_T * 4);
  int*    csr_src = (int*)take((size_t)E * 4);
  __half* Hh      = (__half*)take((size_t)N * 64 * 2);
  float*  Gf      = (float*)take((size_t)N * 64 * 4);
  if (off > ws_size) return;

  const int nb = (N + SCAN_B - 1) / SCAN_B;           // 49
  const int PS = (N + NPART - 1) / NPART;             // 12500
  const int nchunks = (E + ECHUNK - 1) / ECHUNK;      // 489
  const int partGrid = nchunks * NPART;               // 3912

  hipMemsetAsync(d_ws, 0, zeroB, stream);
  k_count_deg<<<partGrid, 256, 0, stream>>>(dst, deg, E, PS);
  k_scan1<<<nb, SCAN_T, 0, stream>>>(deg, rowptr, bsum, N);
  k_scan2<<<1, SCAN_T, 0, stream>>>(bsum, nb);
  k_scan3<<<(N + 255) / 256, 256, 0, stream>>>(rowptr, fillc, bsum, deg, dinv, N, E);
  k_fill<<<partGrid, 256, 0, stream>>>(src, dst, fillc, csr_src, E, PS);

  // layer 1
  k_gemm<128, 64><<<(N + 63) / 64, 256, 0, stream>>>(x, W1, dinv, Hh, N);
  k_agg<64, true><<<(N + 3) / 4, 256, 0, stream>>>(Hh, Gf, rowptr, csr_src,
                                                   dinv, b1, g1, be1, m1, v1, N);
  // layer 2
  k_gemm<64, 64><<<(N + 63) / 64, 256, 0, stream>>>(Gf, W2, dinv, Hh, N);
  k_agg<64, true><<<(N + 3) / 4, 256, 0, stream>>>(Hh, Gf, rowptr, csr_src,
                                                   dinv, b2, g2, be2, m2, v2, N);
  // output layer
  k_gemm<64, 40><<<(N + 99) / 100, 256, 0, stream>>>(Gf, W3, dinv, Hh, N);
  k_agg<40, false><<<(N + 3) / 4, 256, 0, stream>>>(
      Hh, (float*)d_out, rowptr, csr_src, dinv, b3, nullptr, nullptr, nullptr,
      nullptr, N);
}